// Round 8
// baseline (346.101 us; speedup 1.0000x reference)
//
#include <hip/hip_runtime.h>
#include <hip/hip_bf16.h>
#include <math.h>

typedef __bf16 bf16;
typedef unsigned short u16;
typedef unsigned int u32;
typedef __attribute__((ext_vector_type(8))) __bf16 bf16x8;
typedef __attribute__((ext_vector_type(16))) float f32x16;
typedef __attribute__((address_space(1))) void gvoid;
typedef __attribute__((address_space(3))) void svoid;

#define ENT_N 100000
#define REL_N 2000
#define ENT_CH 120        // partial chunks per qgroup (ent)
#define REL_CH 4          // partial chunks per (side,qgroup) (rel)

// ---------------------------------------------------------------------------
// prep_copy: blocks 0..127 linear projections -> bf16 q; 128..383 passthrough.
// ---------------------------------------------------------------------------
__global__ __launch_bounds__(256) void prep_copy(
    const float* __restrict__ query,
    const float* __restrict__ W_left, const float* __restrict__ b_left,
    const float* __restrict__ W_right, const float* __restrict__ b_right,
    const float* __restrict__ W_ent, const float* __restrict__ b_ent,
    const float* __restrict__ lc, const float* __restrict__ rc,
    bf16* __restrict__ qe, bf16* __restrict__ ql, bf16* __restrict__ qr,
    float* __restrict__ out)
{
    __shared__ float qs[4 * 768];
    const int t = threadIdx.x;
    if (blockIdx.x >= 128) {
        const int idx = (blockIdx.x - 128) * 256 + t;
        if (idx < 32768) {
            const int q = idx >> 6, e4 = idx & 63;
            float4 v = *(const float4*)(lc + (size_t)q * 768 + e4 * 4);
            *(float4*)(out + (size_t)q * 768 + e4 * 4) = v;
        } else {
            const int j = idx - 32768;
            const int q = j >> 6, e4 = j & 63;
            float4 v = *(const float4*)(rc + (size_t)q * 768 + 512 + e4 * 4);
            *(float4*)(out + (size_t)393216 + q * 768 + 512 + e4 * 4) = v;
        }
        return;
    }
    const int b0 = blockIdx.x * 4;
#pragma unroll
    for (int i = 0; i < 12; ++i)
        qs[t + 256 * i] = query[(size_t)b0 * 768 + t + 256 * i];
    __syncthreads();

    const int j = t;
    float ae[4], al[4], ar[4];
    const float be = b_ent[j], bl = b_left[j], br = b_right[j];
#pragma unroll
    for (int r = 0; r < 4; ++r) { ae[r] = be; al[r] = bl; ar[r] = br; }

    const float* we = W_ent + (size_t)j * 768;
    for (int k = 0; k < 768; k += 4) {
        const float4 wv = *(const float4*)(we + k);
#pragma unroll
        for (int r = 0; r < 4; ++r) {
            const float* qq = qs + r * 768 + k;
            ae[r] += wv.x * qq[0] + wv.y * qq[1] + wv.z * qq[2] + wv.w * qq[3];
        }
    }
    const float* wl = W_left + (size_t)j * 256;
    const float* wr = W_right + (size_t)j * 256;
    for (int k = 0; k < 256; k += 4) {
        const float4 w1 = *(const float4*)(wl + k);
        const float4 w2 = *(const float4*)(wr + k);
#pragma unroll
        for (int r = 0; r < 4; ++r) {
            const float* qq = qs + r * 768 + 256 + k;
            al[r] += w1.x * qq[0] + w1.y * qq[1] + w1.z * qq[2] + w1.w * qq[3];
            ar[r] += w2.x * qq[0] + w2.y * qq[1] + w2.z * qq[2] + w2.w * qq[3];
        }
    }
#pragma unroll
    for (int r = 0; r < 4; ++r) {
        qe[(size_t)(b0 + r) * 256 + j] = (bf16)ae[r];
        ql[(size_t)(b0 + r) * 256 + j] = (bf16)al[r];
        qr[(size_t)(b0 + r) * 256 + j] = (bf16)ar[r];
    }
}

// ---------------------------------------------------------------------------
// conv_fused (unchanged from r6): fp32 tables -> row-major bf16 K (direct
// from staging regs) + 32-row block-major bf16 V^T (via stride-65 LDS tile).
// ---------------------------------------------------------------------------
__global__ __launch_bounds__(256) void conv_fused(
    const float* __restrict__ entF, const float* __restrict__ relF,
    u16* __restrict__ entT, u16* __restrict__ entB,
    u16* __restrict__ relT, u16* __restrict__ relB)
{
    const float* in; u16* outT; u16* outB; int R; int r0;
    if (blockIdx.x < 1563) {
        in = entF; outT = entT; outB = entB; R = ENT_N; r0 = blockIdx.x * 64;
    } else {
        in = relF; outT = relT; outB = relB; R = REL_N;
        r0 = (blockIdx.x - 1563) * 64;
    }
    __shared__ float tile[64 * 65];
    const int t = threadIdx.x;
    const int e0 = blockIdx.y * 64;

    const int eg = t & 7, rowb = t >> 3;
#pragma unroll
    for (int item = 0; item < 2; ++item) {
        const int r = rowb + item * 32;
        const bool valid = (r0 + r) < R;
        float4 a, b;
        if (valid) {
            const float* src = in + (size_t)(r0 + r) * 256 + e0 + eg * 8;
            a = *(const float4*)src;
            b = *(const float4*)(src + 4);
        } else { a = make_float4(0.f, 0.f, 0.f, 0.f); b = a; }
        float* dst = tile + r * 65 + eg * 8;
        dst[0] = a.x; dst[1] = a.y; dst[2] = a.z; dst[3] = a.w;
        dst[4] = b.x; dst[5] = b.y; dst[6] = b.z; dst[7] = b.w;
        if (valid) {
            bf16x8 v;
            v[0] = (bf16)a.x; v[1] = (bf16)a.y; v[2] = (bf16)a.z; v[3] = (bf16)a.w;
            v[4] = (bf16)b.x; v[5] = (bf16)b.y; v[6] = (bf16)b.z; v[7] = (bf16)b.w;
            *(bf16x8*)(outB + (size_t)(r0 + r) * 256 + e0 + eg * 8) = v;
        }
    }
    __syncthreads();

    const int el = t >> 2, rg = t & 3;
#pragma unroll
    for (int item = 0; item < 2; ++item) {
        const int rp = rg * 8 + item * 32;
        bf16x8 v;
#pragma unroll
        for (int i = 0; i < 8; ++i)
            v[i] = (bf16)tile[(rp + i) * 65 + el];
        const int blk32 = (r0 + rp) >> 5;
        *(bf16x8*)(outT + (size_t)blk32 * 8192 + (e0 + el) * 32 + (rp & 31)) = v;
    }
}

// ---------------------------------------------------------------------------
// flash7: shared-A dual-accumulation. 256 blocks x 256 thr, 1 wave/SIMD.
// Each wave owns 64 q (two 32-q B-fragments); every LDS A-read (K row frag /
// V^T frag) feeds TWO MFMAs -> per-q LDS traffic halved vs flash5 (the
// measured binding pipe). 32-row tiles, double-buffered, async staging.
// No-max softmax; partials summed in combine. Registers ~460 unified
// (qf 128 VGPR + acc 256 AGPR) -> __launch_bounds__(256,1).
// ---------------------------------------------------------------------------
__global__ __launch_bounds__(256, 1) void flash7(
    const bf16* __restrict__ qeP, const bf16* __restrict__ qlP,
    const bf16* __restrict__ qrP,
    const u16* __restrict__ entB, const u16* __restrict__ relB,
    const u16* __restrict__ entT, const u16* __restrict__ relT,
    float* __restrict__ entL, float* __restrict__ relLL,
    float* __restrict__ relLR,
    u16* __restrict__ entO, u16* __restrict__ relOL, u16* __restrict__ relOR)
{
    const int tid = threadIdx.x;
    const int w = tid >> 6;
    const int lane = tid & 63;
    const int n = lane & 31;
    const int kb = lane >> 5;

    int qg, c, stride, nt, Nrows;
    const bf16* qbf; const u16* tabB; const u16* tabT;
    float* pL; u16* pO;
    {
        const int id = blockIdx.x;
        if (id < 240) {                       // ent: 2 qgroups x 120 chunks
            qg = id / 120; c = id % 120;
            stride = 120; nt = (c < 5) ? 27 : 26;   // 3125 = 120*26 + 5
            Nrows = ENT_N;
            qbf = qeP; tabB = entB; tabT = entT; pL = entL; pO = entO;
        } else {                              // rel: 2 sides x 2 qg x 4 chunks
            const int r = id - 240;
            qg = (r >> 2) & 1; c = r & 3;
            stride = 4; nt = (c < 3) ? 16 : 15;     // 63 = 4*15 + 3
            Nrows = REL_N;
            tabB = relB; tabT = relT;
            if (r < 8) { qbf = qlP; pL = relLL; pO = relOL; }
            else       { qbf = qrP; pL = relLR; pO = relOR; }
        }
    }
    const int q0 = qg * 256;
    const int qwA = q0 + w * 64;      // first 32-q subtile of this wave
    const int qwB = qwA + 32;         // second

    // 64 KB LDS: buf{0,1} x (sK 16 KB [kc32][row32] + sV 16 KB [rc4][e256])
    __shared__ __align__(16) u16 lds[32768];

    bf16x8 qfA[16], qfB[16];
#pragma unroll
    for (int ks = 0; ks < 16; ++ks) {
        qfA[ks] = *(const bf16x8*)(qbf + (size_t)(qwA + n) * 256 + ks * 16 + kb * 8);
        qfB[ks] = *(const bf16x8*)(qbf + (size_t)(qwB + n) * 256 + ks * 16 + kb * 8);
    }

    f32x16 accA[8], accB[8];
#pragma unroll
    for (int et = 0; et < 8; ++et)
#pragma unroll
        for (int i = 0; i < 16; ++i) { accA[et][i] = 0.f; accB[et][i] = 0.f; }
    float lA = 0.f, lB = 0.f;

    auto stage = [&](int buf, int rt) {
        u16* sK = lds + buf * 16384;
        u16* sV = sK + 8192;
        const u16* kbase = tabB + (size_t)min(rt * 32 + n, Nrows - 1) * 256 + kb * 8;
#pragma unroll
        for (int i = 0; i < 4; ++i) {
            const int k64 = w * 4 + i;
            __builtin_amdgcn_global_load_lds(
                (gvoid*)(kbase + k64 * 16),
                (svoid*)(sK + k64 * 512), 16, 0, 0);
        }
        const u16* vbase = tabT + (size_t)rt * 8192 + (size_t)lane * 32 + w * 8;
#pragma unroll
        for (int i = 0; i < 4; ++i)
            __builtin_amdgcn_global_load_lds(
                (gvoid*)(vbase + i * 2048),
                (svoid*)(sV + w * 2048 + i * 512), 16, 0, 0);
    };

    int rt = c;
    stage(0, rt);
    __syncthreads();

    for (int k = 0; k < nt; ++k) {
        if (k + 1 < nt) stage((k + 1) & 1, rt + stride);

        const u16* sK = lds + (k & 1) * 16384;
        const u16* sV = sK + 8192;
        const int gr = rt * 32;

        // ---- QK: shared A read feeds both q-subtiles ----
        f32x16 L0, L1;
#pragma unroll
        for (int i = 0; i < 16; ++i) { L0[i] = 0.f; L1[i] = 0.f; }
#pragma unroll
        for (int ks = 0; ks < 16; ++ks) {
            const int kc = ks * 2 + kb;
            bf16x8 a = *(bf16x8*)(sK + (size_t)(kc * 32 + n) * 8);
            L0 = __builtin_amdgcn_mfma_f32_32x32x16_bf16(a, qfA[ks], L0, 0, 0, 0);
            L1 = __builtin_amdgcn_mfma_f32_32x32x16_bf16(a, qfB[ks], L1, 0, 0, 0);
        }
        if (gr + 32 > Nrows) {
#pragma unroll
            for (int r = 0; r < 16; ++r) {
                const int row = (r & 3) + 8 * (r >> 2) + 4 * kb;
                if (gr + row >= Nrows) { L0[r] = -1e30f; L1[r] = -1e30f; }
            }
        }
        // ---- P = exp(L); repack C->B layout (cross-half shfl) ----
        float rsA = 0.f, rsB = 0.f;
#pragma unroll
        for (int r = 0; r < 16; ++r) {
            const float pA = __expf(L0[r]); L0[r] = pA; rsA += pA;
            const float pB = __expf(L1[r]); L1[r] = pB; rsB += pB;
        }
        rsA += __shfl_xor(rsA, 32); lA += rsA;
        rsB += __shfl_xor(rsB, 32); lB += rsB;

        bf16x8 bpA0, bpA1, bpB0, bpB1;
#pragma unroll
        for (int r2 = 0; r2 < 4; ++r2) {
#pragma unroll
            for (int ks2 = 0; ks2 < 2; ++ks2) {
                const int a_ = r2 + 8 * ks2;
                {
                    const float own  = kb ? L0[a_ + 4] : L0[a_];
                    const float csrc = kb ? L0[a_]     : L0[a_ + 4];
                    const float cross = __shfl_xor(csrc, 32);
                    bf16 v0 = (bf16)(kb ? cross : own);
                    bf16 v1 = (bf16)(kb ? own : cross);
                    if (ks2 == 0) { bpA0[r2] = v0; bpA0[r2 + 4] = v1; }
                    else          { bpA1[r2] = v0; bpA1[r2 + 4] = v1; }
                }
                {
                    const float own  = kb ? L1[a_ + 4] : L1[a_];
                    const float csrc = kb ? L1[a_]     : L1[a_ + 4];
                    const float cross = __shfl_xor(csrc, 32);
                    bf16 v0 = (bf16)(kb ? cross : own);
                    bf16 v1 = (bf16)(kb ? own : cross);
                    if (ks2 == 0) { bpB0[r2] = v0; bpB0[r2 + 4] = v1; }
                    else          { bpB1[r2] = v0; bpB1[r2 + 4] = v1; }
                }
            }
        }
        // ---- PV: shared V read feeds both q-subtiles ----
#pragma unroll
        for (int ks2 = 0; ks2 < 2; ++ks2) {
            const bf16x8 bA = ks2 ? bpA1 : bpA0;
            const bf16x8 bB = ks2 ? bpB1 : bpB0;
            const int rc = ks2 * 2 + kb;
#pragma unroll
            for (int et = 0; et < 8; ++et) {
                bf16x8 av = *(bf16x8*)(sV + (size_t)(rc * 256 + et * 32 + n) * 8);
                accA[et] = __builtin_amdgcn_mfma_f32_32x32x16_bf16(av, bA, accA[et], 0, 0, 0);
                accB[et] = __builtin_amdgcn_mfma_f32_32x32x16_bf16(av, bB, accB[et], 0, 0, 0);
            }
        }
        rt += stride;
        __syncthreads();
    }

    // ---- write partial l ----
    if (lane < 32) {
        pL[(size_t)c * 512 + qwA + n] = lA;
        pL[(size_t)c * 512 + qwB + n] = lB;
    }

    // ---- write partial O via LDS transpose: 4 rounds (2 subtiles x 2 halves)
    for (int sub = 0; sub < 2; ++sub) {
        for (int half = 0; half < 2; ++half) {
            __syncthreads();
            if ((w >> 1) == half) {
                u16* rgn = lds + (w & 1) * 8448;   // [32 q][264]
#pragma unroll
                for (int et = 0; et < 8; ++et)
#pragma unroll
                    for (int a2 = 0; a2 < 4; ++a2) {
                        const f32x16& ac = sub ? accB[et] : accA[et];
                        bf16 h0 = (bf16)ac[a2 * 4 + 0];
                        bf16 h1 = (bf16)ac[a2 * 4 + 1];
                        bf16 h2 = (bf16)ac[a2 * 4 + 2];
                        bf16 h3 = (bf16)ac[a2 * 4 + 3];
                        uint2 pk;
                        pk.x = ((u32)(*(u16*)&h1) << 16) | (u32)(*(u16*)&h0);
                        pk.y = ((u32)(*(u16*)&h3) << 16) | (u32)(*(u16*)&h2);
                        *(uint2*)(rgn + n * 264 + et * 32 + 8 * a2 + 4 * kb) = pk;
                    }
            }
            __syncthreads();
#pragma unroll
            for (int rg = 0; rg < 2; ++rg) {
                const int qt2 = q0 + (half * 2 + rg) * 64 + sub * 32;
                const u16* src = lds + rg * 8448;
                const int qq = tid >> 3, e0 = (tid & 7) * 32;
#pragma unroll
                for (int i = 0; i < 4; ++i) {
                    const u16* sp = src + qq * 264 + e0 + i * 8;
                    uint2 a = *(const uint2*)(sp);
                    uint2 b = *(const uint2*)(sp + 4);
                    uint4 wv; wv.x = a.x; wv.y = a.y; wv.z = b.x; wv.w = b.y;
                    *(uint4*)(pO + ((size_t)c * 512 + qt2 + qq) * 256 + e0 + i * 8) = wv;
                }
            }
        }
    }
}

// ---------------------------------------------------------------------------
// combine_all: grid (64, 3): y=0 ent (CH=120), y=1 relL, y=2 relR (CH=4).
// ---------------------------------------------------------------------------
__global__ __launch_bounds__(256) void combine_all(
    const u16* __restrict__ entO, const float* __restrict__ entL,
    const u16* __restrict__ relOL, const float* __restrict__ relLL,
    const u16* __restrict__ relOR, const float* __restrict__ relLR,
    float* __restrict__ out)
{
    const u16* pO; const float* pl; int CH, baseA, baseB;
    if (blockIdx.y == 0) { pO = entO; pl = entL; CH = ENT_CH; baseA = 512; baseB = 393216; }
    else if (blockIdx.y == 1) { pO = relOL; pl = relLL; CH = REL_CH; baseA = 256; baseB = -1; }
    else { pO = relOR; pl = relLR; CH = REL_CH; baseA = 393472; baseB = -1; }

    const int idx = blockIdx.x * 256 + threadIdx.x;
    const int q = idx >> 5;
    const int e0 = (idx & 31) * 8;
    float s = 0.f;
#pragma unroll 4
    for (int c = 0; c < CH; ++c) s += pl[(size_t)c * 512 + q];
    const float inv = 1.f / s;
    float a[8];
#pragma unroll
    for (int k = 0; k < 8; ++k) a[k] = 0.f;
#pragma unroll 4
    for (int c = 0; c < CH; ++c) {
        const uint4 wv = *(const uint4*)(pO + ((size_t)c * 512 + q) * 256 + e0);
        const u32 ww[4] = {wv.x, wv.y, wv.z, wv.w};
#pragma unroll
        for (int p = 0; p < 4; ++p) {
            a[p * 2]     += __uint_as_float((ww[p] & 0xffffu) << 16);
            a[p * 2 + 1] += __uint_as_float(ww[p] & 0xffff0000u);
        }
    }
#pragma unroll
    for (int k = 0; k < 8; ++k) a[k] *= inv;
    float4 o1 = {a[0], a[1], a[2], a[3]};
    float4 o2 = {a[4], a[5], a[6], a[7]};
    *(float4*)(out + (size_t)baseA + (size_t)q * 768 + e0) = o1;
    *(float4*)(out + (size_t)baseA + (size_t)q * 768 + e0 + 4) = o2;
    if (baseB >= 0) {
        *(float4*)(out + (size_t)baseB + (size_t)q * 768 + e0) = o1;
        *(float4*)(out + (size_t)baseB + (size_t)q * 768 + e0 + 4) = o2;
    }
}

// ---------------------------------------------------------------------------
// Fallback (small ws): fp32 online-softmax attend, bf16 q input.
// ---------------------------------------------------------------------------
__global__ __launch_bounds__(256) void attend_simple(
    const bf16* __restrict__ qbf, const float* __restrict__ tab, int Nrows,
    float* __restrict__ out, int baseA, int baseB)
{
    const int q = blockIdx.x;
    const int t = threadIdx.x, wave = t >> 6, lane = t & 63;
    float qv[4];
#pragma unroll
    for (int i = 0; i < 4; ++i) qv[i] = (float)qbf[(size_t)q * 256 + lane + 64 * i];
    float m = -INFINITY, l = 0.f, o[4] = {0.f, 0.f, 0.f, 0.f};
    for (int r = wave; r < Nrows; r += 4) {
        const float* row = tab + (size_t)r * 256;
        float d = 0.f;
#pragma unroll
        for (int i = 0; i < 4; ++i) d += qv[i] * row[lane + 64 * i];
#pragma unroll
        for (int s = 32; s; s >>= 1) d += __shfl_xor(d, s);
        const float mn = fmaxf(m, d);
        const float al = __expf(m - mn);
        const float p = __expf(d - mn);
#pragma unroll
        for (int i = 0; i < 4; ++i) o[i] = o[i] * al + p * row[lane + 64 * i];
        l = l * al + p; m = mn;
    }
    __shared__ float sm[4], sl[4], so[4][256];
    if (lane == 0) { sm[wave] = m; sl[wave] = l; }
#pragma unroll
    for (int i = 0; i < 4; ++i) so[wave][lane + 64 * i] = o[i];
    __syncthreads();
    const float M = fmaxf(fmaxf(sm[0], sm[1]), fmaxf(sm[2], sm[3]));
    const float w0 = __expf(sm[0] - M), w1 = __expf(sm[1] - M);
    const float w2 = __expf(sm[2] - M), w3 = __expf(sm[3] - M);
    const float L = w0 * sl[0] + w1 * sl[1] + w2 * sl[2] + w3 * sl[3];
    const float a = (w0 * so[0][t] + w1 * so[1][t] + w2 * so[2][t] + w3 * so[3][t]) / L;
    out[(size_t)baseA + (size_t)q * 768 + t] = a;
    if (baseB >= 0) out[(size_t)baseB + (size_t)q * 768 + t] = a;
}

// ---------------------------------------------------------------------------
extern "C" void kernel_launch(void* const* d_in, const int* in_sizes, int n_in,
                              void* d_out, int out_size, void* d_ws, size_t ws_size,
                              hipStream_t stream)
{
    const float* left_child  = (const float*)d_in[0];
    const float* right_child = (const float*)d_in[1];
    const float* query       = (const float*)d_in[2];
    const float* ent_emb     = (const float*)d_in[3];
    const float* rel_emb     = (const float*)d_in[4];
    const float* W_left      = (const float*)d_in[5];
    const float* b_left      = (const float*)d_in[6];
    const float* W_right     = (const float*)d_in[7];
    const float* b_right     = (const float*)d_in[8];
    const float* W_ent       = (const float*)d_in[9];
    const float* b_ent       = (const float*)d_in[10];
    float* out = (float*)d_out;
    char* ws = (char*)d_ws;

    // ws layout (bytes)
    bf16*  qe_bf = (bf16*)(ws + 0);            //    262,144
    bf16*  ql_bf = (bf16*)(ws + 262144);       //    262,144
    bf16*  qr_bf = (bf16*)(ws + 524288);       //    262,144
    u16*   entT  = (u16*)(ws + 786432);        // 51,216,384 (3126 blk32 x 16 KB)
    u16*   relT  = (u16*)(ws + 52002816);      //  1,048,576 (64 blk32 x 16 KB)
    u16*   entB  = (u16*)(ws + 53051392);      // 51,200,000
    u16*   relB  = (u16*)(ws + 104251392);     //  1,024,000
    float* entL  = (float*)(ws + 105275392);   //    245,760 (120*512*4)
    u16*   entO  = (u16*)(ws + 105521152);     // 31,457,280 (120*512*256*2)
    float* relLL = (float*)(ws + 136978432);   //      8,192
    float* relLR = (float*)(ws + 136986624);   //      8,192
    u16*   relOL = (u16*)(ws + 136994816);     //  1,048,576
    u16*   relOR = (u16*)(ws + 138043392);     //  1,048,576
    const size_t WS_FULL = 139091968;          // <= 145,655,808 (established)
    const size_t WS_FALLBACK = 786432;

    prep_copy<<<dim3(384), dim3(256), 0, stream>>>(
        query, W_left, b_left, W_right, b_right, W_ent, b_ent,
        left_child, right_child, qe_bf, ql_bf, qr_bf, out);

    if (ws_size >= WS_FULL) {
        conv_fused<<<dim3(1595, 4), dim3(256), 0, stream>>>(
            ent_emb, rel_emb, entT, entB, relT, relB);
        flash7<<<dim3(256), dim3(256), 0, stream>>>(
            qe_bf, ql_bf, qr_bf, entB, relB, entT, relT,
            entL, relLL, relLR, entO, relOL, relOR);
        combine_all<<<dim3(64, 3), dim3(256), 0, stream>>>(
            entO, entL, relOL, relLL, relOR, relLR, out);
    } else if (ws_size >= WS_FALLBACK) {
        attend_simple<<<dim3(512), dim3(256), 0, stream>>>(qe_bf, ent_emb, ENT_N, out, 512, 393216);
        attend_simple<<<dim3(512), dim3(256), 0, stream>>>(ql_bf, rel_emb, REL_N, out, 256, -1);
        attend_simple<<<dim3(512), dim3(256), 0, stream>>>(qr_bf, rel_emb, REL_N, out, 393472, -1);
    }
    (void)in_sizes; (void)n_in; (void)out_size;
}

// Round 9
// 324.659 us; speedup vs baseline: 1.0660x; 1.0660x over previous
//
#include <hip/hip_runtime.h>
#include <hip/hip_bf16.h>
#include <math.h>

typedef __bf16 bf16;
typedef unsigned short u16;
typedef unsigned int u32;
typedef __attribute__((ext_vector_type(8))) __bf16 bf16x8;
typedef __attribute__((ext_vector_type(16))) float f32x16;
typedef __attribute__((address_space(1))) void gvoid;
typedef __attribute__((address_space(3))) void svoid;

#define ENT_N 100000
#define REL_N 2000
#define ENT_CH 120        // partial chunks per qt (ent)
#define REL_CH 4          // partial chunks per (side,qt) (rel)

// ---------------------------------------------------------------------------
// prep_copy: blocks 0..127 linear projections -> bf16 q; 128..383 passthrough.
// ---------------------------------------------------------------------------
__global__ __launch_bounds__(256) void prep_copy(
    const float* __restrict__ query,
    const float* __restrict__ W_left, const float* __restrict__ b_left,
    const float* __restrict__ W_right, const float* __restrict__ b_right,
    const float* __restrict__ W_ent, const float* __restrict__ b_ent,
    const float* __restrict__ lc, const float* __restrict__ rc,
    bf16* __restrict__ qe, bf16* __restrict__ ql, bf16* __restrict__ qr,
    float* __restrict__ out)
{
    __shared__ float qs[4 * 768];
    const int t = threadIdx.x;
    if (blockIdx.x >= 128) {
        const int idx = (blockIdx.x - 128) * 256 + t;
        if (idx < 32768) {
            const int q = idx >> 6, e4 = idx & 63;
            float4 v = *(const float4*)(lc + (size_t)q * 768 + e4 * 4);
            *(float4*)(out + (size_t)q * 768 + e4 * 4) = v;
        } else {
            const int j = idx - 32768;
            const int q = j >> 6, e4 = j & 63;
            float4 v = *(const float4*)(rc + (size_t)q * 768 + 512 + e4 * 4);
            *(float4*)(out + (size_t)393216 + q * 768 + 512 + e4 * 4) = v;
        }
        return;
    }
    const int b0 = blockIdx.x * 4;
#pragma unroll
    for (int i = 0; i < 12; ++i)
        qs[t + 256 * i] = query[(size_t)b0 * 768 + t + 256 * i];
    __syncthreads();

    const int j = t;
    float ae[4], al[4], ar[4];
    const float be = b_ent[j], bl = b_left[j], br = b_right[j];
#pragma unroll
    for (int r = 0; r < 4; ++r) { ae[r] = be; al[r] = bl; ar[r] = br; }

    const float* we = W_ent + (size_t)j * 768;
    for (int k = 0; k < 768; k += 4) {
        const float4 wv = *(const float4*)(we + k);
#pragma unroll
        for (int r = 0; r < 4; ++r) {
            const float* qq = qs + r * 768 + k;
            ae[r] += wv.x * qq[0] + wv.y * qq[1] + wv.z * qq[2] + wv.w * qq[3];
        }
    }
    const float* wl = W_left + (size_t)j * 256;
    const float* wr = W_right + (size_t)j * 256;
    for (int k = 0; k < 256; k += 4) {
        const float4 w1 = *(const float4*)(wl + k);
        const float4 w2 = *(const float4*)(wr + k);
#pragma unroll
        for (int r = 0; r < 4; ++r) {
            const float* qq = qs + r * 768 + 256 + k;
            al[r] += w1.x * qq[0] + w1.y * qq[1] + w1.z * qq[2] + w1.w * qq[3];
            ar[r] += w2.x * qq[0] + w2.y * qq[1] + w2.z * qq[2] + w2.w * qq[3];
        }
    }
#pragma unroll
    for (int r = 0; r < 4; ++r) {
        qe[(size_t)(b0 + r) * 256 + j] = (bf16)ae[r];
        ql[(size_t)(b0 + r) * 256 + j] = (bf16)al[r];
        qr[(size_t)(b0 + r) * 256 + j] = (bf16)ar[r];
    }
}

// ---------------------------------------------------------------------------
// conv_fused v3: fp32 tables -> row-major bf16 K (direct from staging regs) +
// 32-row block-major bf16 V^T with rows PERMUTED inside each 32-row block to
// match the MFMA C-layout: table row (j&3)+8*(j>>2)+4*kb+16*ks2 is stored at
// slot ks2*16+kb*8+j. Per aligned 4-row group b (=row>>2) the slot group is
// sb = (b&4)|((b&1)<<1)|((b>>1)&1) (swap low two bits). This makes flash's
// P-repack shuffle-free: B-fragment = L registers in order.
// ---------------------------------------------------------------------------
__global__ __launch_bounds__(256) void conv_fused(
    const float* __restrict__ entF, const float* __restrict__ relF,
    u16* __restrict__ entT, u16* __restrict__ entB,
    u16* __restrict__ relT, u16* __restrict__ relB)
{
    const float* in; u16* outT; u16* outB; int R; int r0;
    if (blockIdx.x < 1563) {
        in = entF; outT = entT; outB = entB; R = ENT_N; r0 = blockIdx.x * 64;
    } else {
        in = relF; outT = relT; outB = relB; R = REL_N;
        r0 = (blockIdx.x - 1563) * 64;
    }
    __shared__ float tile[64 * 65];
    const int t = threadIdx.x;
    const int e0 = blockIdx.y * 64;

    const int eg = t & 7, rowb = t >> 3;
#pragma unroll
    for (int item = 0; item < 2; ++item) {
        const int r = rowb + item * 32;
        const bool valid = (r0 + r) < R;
        float4 a, b;
        if (valid) {
            const float* src = in + (size_t)(r0 + r) * 256 + e0 + eg * 8;
            a = *(const float4*)src;
            b = *(const float4*)(src + 4);
        } else { a = make_float4(0.f, 0.f, 0.f, 0.f); b = a; }
        float* dst = tile + r * 65 + eg * 8;
        dst[0] = a.x; dst[1] = a.y; dst[2] = a.z; dst[3] = a.w;
        dst[4] = b.x; dst[5] = b.y; dst[6] = b.z; dst[7] = b.w;
        if (valid) {
            bf16x8 v;
            v[0] = (bf16)a.x; v[1] = (bf16)a.y; v[2] = (bf16)a.z; v[3] = (bf16)a.w;
            v[4] = (bf16)b.x; v[5] = (bf16)b.y; v[6] = (bf16)b.z; v[7] = (bf16)b.w;
            *(bf16x8*)(outB + (size_t)(r0 + r) * 256 + e0 + eg * 8) = v;
        }
    }
    __syncthreads();

    // V emit with per-4-row-group permutation (two 8 B stores per item)
    const int el = t >> 2, rg = t & 3;
#pragma unroll
    for (int item = 0; item < 2; ++item) {
        const int rp = rg * 8 + item * 32;
        const int blk32 = (r0 + rp) >> 5;
#pragma unroll
        for (int h = 0; h < 2; ++h) {
            const int b = ((rp & 31) >> 2) + h;
            const int sb = (b & 4) | ((b & 1) << 1) | ((b >> 1) & 1);
            bf16 v0 = (bf16)tile[(rp + 4 * h + 0) * 65 + el];
            bf16 v1 = (bf16)tile[(rp + 4 * h + 1) * 65 + el];
            bf16 v2 = (bf16)tile[(rp + 4 * h + 2) * 65 + el];
            bf16 v3 = (bf16)tile[(rp + 4 * h + 3) * 65 + el];
            uint2 pk;
            pk.x = ((u32)(*(u16*)&v1) << 16) | (u32)(*(u16*)&v0);
            pk.y = ((u32)(*(u16*)&v3) << 16) | (u32)(*(u16*)&v2);
            *(uint2*)(outT + (size_t)blk32 * 8192 + (e0 + el) * 32 + sb * 4) = pk;
        }
    }
}

// ---------------------------------------------------------------------------
// flash8: flash5 structure (512-block balanced persistent grid, 32-row tiles,
// double-buffered async staging, 2 blocks/CU) + permuted-V layout so the P
// C->B repack is shuffle-free: bp0 = cvt(L[0..7]), bp1 = cvt(L[8..15]).
// ---------------------------------------------------------------------------
__global__ __launch_bounds__(256, 2) void flash8(
    const bf16* __restrict__ qeP, const bf16* __restrict__ qlP,
    const bf16* __restrict__ qrP,
    const u16* __restrict__ entB, const u16* __restrict__ relB,
    const u16* __restrict__ entT, const u16* __restrict__ relT,
    float* __restrict__ entL, float* __restrict__ relLL,
    float* __restrict__ relLR,
    u16* __restrict__ entO, u16* __restrict__ relOL, u16* __restrict__ relOR)
{
    const int tid = threadIdx.x;
    const int w = tid >> 6;
    const int lane = tid & 63;
    const int n = lane & 31;
    const int kb = lane >> 5;

    int qt, c, stride, nt, Nrows;
    const bf16* qbf; const u16* tabB; const u16* tabT;
    float* pL; u16* pO;
    {
        const int id = blockIdx.x;
        if (id < 480) {
            qt = id / 120; c = id % 120;
            stride = 120; nt = (c < 5) ? 27 : 26;
            Nrows = ENT_N;
            qbf = qeP; tabB = entB; tabT = entT; pL = entL; pO = entO;
        } else {
            const int r = id - 480;
            qt = (r >> 2) & 3; c = r & 3;
            stride = 4; nt = (c < 3) ? 16 : 15;
            Nrows = REL_N;
            tabB = relB; tabT = relT;
            if (r < 16) { qbf = qlP; pL = relLL; pO = relOL; }
            else        { qbf = qrP; pL = relLR; pO = relOR; }
        }
    }
    const int q0 = qt * 128;
    const int qw = q0 + w * 32;

    __shared__ __align__(16) u16 lds[32768];

    bf16x8 qf[16];
#pragma unroll
    for (int ks = 0; ks < 16; ++ks)
        qf[ks] = *(const bf16x8*)(qbf + (size_t)(qw + n) * 256 + ks * 16 + kb * 8);

    f32x16 acc[8];
#pragma unroll
    for (int et = 0; et < 8; ++et)
#pragma unroll
        for (int i = 0; i < 16; ++i) acc[et][i] = 0.f;
    float l_run = 0.f;

    auto stage = [&](int buf, int rt) {
        u16* sK = lds + buf * 16384;
        u16* sV = sK + 8192;
        const u16* kbase = tabB + (size_t)min(rt * 32 + n, Nrows - 1) * 256 + kb * 8;
#pragma unroll
        for (int i = 0; i < 4; ++i) {
            const int k64 = w * 4 + i;
            __builtin_amdgcn_global_load_lds(
                (gvoid*)(kbase + k64 * 16),
                (svoid*)(sK + k64 * 512), 16, 0, 0);
        }
        const u16* vbase = tabT + (size_t)rt * 8192 + (size_t)lane * 32 + w * 8;
#pragma unroll
        for (int i = 0; i < 4; ++i)
            __builtin_amdgcn_global_load_lds(
                (gvoid*)(vbase + i * 2048),
                (svoid*)(sV + w * 2048 + i * 512), 16, 0, 0);
    };

    int rt = c;
    stage(0, rt);
    __syncthreads();

    for (int k = 0; k < nt; ++k) {
        if (k + 1 < nt) stage((k + 1) & 1, rt + stride);

        const u16* sK = lds + (k & 1) * 16384;
        const u16* sV = sK + 8192;
        const int gr = rt * 32;

        // ---- logits^T: D[row=m(table), col=n(q)] ----
        f32x16 L;
#pragma unroll
        for (int i = 0; i < 16; ++i) L[i] = 0.f;
#pragma unroll
        for (int ks = 0; ks < 16; ++ks) {
            const int kc = ks * 2 + kb;
            bf16x8 a = *(bf16x8*)(sK + (size_t)(kc * 32 + n) * 8);
            L = __builtin_amdgcn_mfma_f32_32x32x16_bf16(a, qf[ks], L, 0, 0, 0);
        }
        if (gr + 32 > Nrows) {
#pragma unroll
            for (int r = 0; r < 16; ++r) {
                const int row = (r & 3) + 8 * (r >> 2) + 4 * kb;
                if (gr + row >= Nrows) L[r] = -1e30f;
            }
        }
        // ---- P = exp(L) ----
        float rs = 0.f;
#pragma unroll
        for (int r = 0; r < 16; ++r) {
            const float p = __expf(L[r]);
            L[r] = p; rs += p;
        }
        rs += __shfl_xor(rs, 32);
        l_run += rs;
        // ---- PV: permuted-V layout -> B-fragments are L in register order ----
        bf16x8 bp0, bp1;
#pragma unroll
        for (int j = 0; j < 8; ++j) {
            bp0[j] = (bf16)L[j];
            bp1[j] = (bf16)L[j + 8];
        }
#pragma unroll
        for (int ks2 = 0; ks2 < 2; ++ks2) {
            const bf16x8 bp = ks2 ? bp1 : bp0;
            const int rc = ks2 * 2 + kb;
#pragma unroll
            for (int et = 0; et < 8; ++et) {
                bf16x8 av = *(bf16x8*)(sV + (size_t)(rc * 256 + et * 32 + n) * 8);
                acc[et] = __builtin_amdgcn_mfma_f32_32x32x16_bf16(av, bp, acc[et], 0, 0, 0);
            }
        }
        rt += stride;
        __syncthreads();
    }

    if (lane < 32) pL[(size_t)c * 512 + qw + n] = l_run;

    // ---- write partial O via LDS transpose (stride 264, two wave-pairs) ----
    for (int half = 0; half < 2; ++half) {
        __syncthreads();
        if ((w >> 1) == half) {
            u16* rgn = lds + (w & 1) * 8448;   // [32 q][264]
#pragma unroll
            for (int et = 0; et < 8; ++et)
#pragma unroll
                for (int a2 = 0; a2 < 4; ++a2) {
                    bf16 h0 = (bf16)acc[et][a2 * 4 + 0];
                    bf16 h1 = (bf16)acc[et][a2 * 4 + 1];
                    bf16 h2 = (bf16)acc[et][a2 * 4 + 2];
                    bf16 h3 = (bf16)acc[et][a2 * 4 + 3];
                    uint2 pk;
                    pk.x = ((u32)(*(u16*)&h1) << 16) | (u32)(*(u16*)&h0);
                    pk.y = ((u32)(*(u16*)&h3) << 16) | (u32)(*(u16*)&h2);
                    *(uint2*)(rgn + n * 264 + et * 32 + 8 * a2 + 4 * kb) = pk;
                }
        }
        __syncthreads();
#pragma unroll
        for (int rg = 0; rg < 2; ++rg) {
            const int qt2 = q0 + (half * 2 + rg) * 32;
            const u16* src = lds + rg * 8448;
            const int qq = tid >> 3, e0 = (tid & 7) * 32;
#pragma unroll
            for (int i = 0; i < 4; ++i) {
                const u16* sp = src + qq * 264 + e0 + i * 8;
                uint2 a = *(const uint2*)(sp);
                uint2 b = *(const uint2*)(sp + 4);
                uint4 wv; wv.x = a.x; wv.y = a.y; wv.z = b.x; wv.w = b.y;
                *(uint4*)(pO + ((size_t)c * 512 + qt2 + qq) * 256 + e0 + i * 8) = wv;
            }
        }
    }
}

// ---------------------------------------------------------------------------
// combine_all: grid (64, 3): y=0 ent (CH=120), y=1 relL, y=2 relR (CH=4).
// ---------------------------------------------------------------------------
__global__ __launch_bounds__(256) void combine_all(
    const u16* __restrict__ entO, const float* __restrict__ entL,
    const u16* __restrict__ relOL, const float* __restrict__ relLL,
    const u16* __restrict__ relOR, const float* __restrict__ relLR,
    float* __restrict__ out)
{
    const u16* pO; const float* pl; int CH, baseA, baseB;
    if (blockIdx.y == 0) { pO = entO; pl = entL; CH = ENT_CH; baseA = 512; baseB = 393216; }
    else if (blockIdx.y == 1) { pO = relOL; pl = relLL; CH = REL_CH; baseA = 256; baseB = -1; }
    else { pO = relOR; pl = relLR; CH = REL_CH; baseA = 393472; baseB = -1; }

    const int idx = blockIdx.x * 256 + threadIdx.x;
    const int q = idx >> 5;
    const int e0 = (idx & 31) * 8;
    float s = 0.f;
#pragma unroll 4
    for (int c = 0; c < CH; ++c) s += pl[(size_t)c * 512 + q];
    const float inv = 1.f / s;
    float a[8];
#pragma unroll
    for (int k = 0; k < 8; ++k) a[k] = 0.f;
#pragma unroll 4
    for (int c = 0; c < CH; ++c) {
        const uint4 wv = *(const uint4*)(pO + ((size_t)c * 512 + q) * 256 + e0);
        const u32 ww[4] = {wv.x, wv.y, wv.z, wv.w};
#pragma unroll
        for (int p = 0; p < 4; ++p) {
            a[p * 2]     += __uint_as_float((ww[p] & 0xffffu) << 16);
            a[p * 2 + 1] += __uint_as_float(ww[p] & 0xffff0000u);
        }
    }
#pragma unroll
    for (int k = 0; k < 8; ++k) a[k] *= inv;
    float4 o1 = {a[0], a[1], a[2], a[3]};
    float4 o2 = {a[4], a[5], a[6], a[7]};
    *(float4*)(out + (size_t)baseA + (size_t)q * 768 + e0) = o1;
    *(float4*)(out + (size_t)baseA + (size_t)q * 768 + e0 + 4) = o2;
    if (baseB >= 0) {
        *(float4*)(out + (size_t)baseB + (size_t)q * 768 + e0) = o1;
        *(float4*)(out + (size_t)baseB + (size_t)q * 768 + e0 + 4) = o2;
    }
}

// ---------------------------------------------------------------------------
// Fallback (small ws): fp32 online-softmax attend, bf16 q input.
// ---------------------------------------------------------------------------
__global__ __launch_bounds__(256) void attend_simple(
    const bf16* __restrict__ qbf, const float* __restrict__ tab, int Nrows,
    float* __restrict__ out, int baseA, int baseB)
{
    const int q = blockIdx.x;
    const int t = threadIdx.x, wave = t >> 6, lane = t & 63;
    float qv[4];
#pragma unroll
    for (int i = 0; i < 4; ++i) qv[i] = (float)qbf[(size_t)q * 256 + lane + 64 * i];
    float m = -INFINITY, l = 0.f, o[4] = {0.f, 0.f, 0.f, 0.f};
    for (int r = wave; r < Nrows; r += 4) {
        const float* row = tab + (size_t)r * 256;
        float d = 0.f;
#pragma unroll
        for (int i = 0; i < 4; ++i) d += qv[i] * row[lane + 64 * i];
#pragma unroll
        for (int s = 32; s; s >>= 1) d += __shfl_xor(d, s);
        const float mn = fmaxf(m, d);
        const float al = __expf(m - mn);
        const float p = __expf(d - mn);
#pragma unroll
        for (int i = 0; i < 4; ++i) o[i] = o[i] * al + p * row[lane + 64 * i];
        l = l * al + p; m = mn;
    }
    __shared__ float sm[4], sl[4], so[4][256];
    if (lane == 0) { sm[wave] = m; sl[wave] = l; }
#pragma unroll
    for (int i = 0; i < 4; ++i) so[wave][lane + 64 * i] = o[i];
    __syncthreads();
    const float M = fmaxf(fmaxf(sm[0], sm[1]), fmaxf(sm[2], sm[3]));
    const float w0 = __expf(sm[0] - M), w1 = __expf(sm[1] - M);
    const float w2 = __expf(sm[2] - M), w3 = __expf(sm[3] - M);
    const float L = w0 * sl[0] + w1 * sl[1] + w2 * sl[2] + w3 * sl[3];
    const float a = (w0 * so[0][t] + w1 * so[1][t] + w2 * so[2][t] + w3 * so[3][t]) / L;
    out[(size_t)baseA + (size_t)q * 768 + t] = a;
    if (baseB >= 0) out[(size_t)baseB + (size_t)q * 768 + t] = a;
}

// ---------------------------------------------------------------------------
extern "C" void kernel_launch(void* const* d_in, const int* in_sizes, int n_in,
                              void* d_out, int out_size, void* d_ws, size_t ws_size,
                              hipStream_t stream)
{
    const float* left_child  = (const float*)d_in[0];
    const float* right_child = (const float*)d_in[1];
    const float* query       = (const float*)d_in[2];
    const float* ent_emb     = (const float*)d_in[3];
    const float* rel_emb     = (const float*)d_in[4];
    const float* W_left      = (const float*)d_in[5];
    const float* b_left      = (const float*)d_in[6];
    const float* W_right     = (const float*)d_in[7];
    const float* b_right     = (const float*)d_in[8];
    const float* W_ent       = (const float*)d_in[9];
    const float* b_ent       = (const float*)d_in[10];
    float* out = (float*)d_out;
    char* ws = (char*)d_ws;

    // ws layout (bytes)
    bf16*  qe_bf = (bf16*)(ws + 0);            //    262,144
    bf16*  ql_bf = (bf16*)(ws + 262144);       //    262,144
    bf16*  qr_bf = (bf16*)(ws + 524288);       //    262,144
    u16*   entT  = (u16*)(ws + 786432);        // 51,216,384 (3126 blk32 x 16 KB)
    u16*   relT  = (u16*)(ws + 52002816);      //  1,048,576 (64 blk32 x 16 KB)
    u16*   entB  = (u16*)(ws + 53051392);      // 51,200,000
    u16*   relB  = (u16*)(ws + 104251392);     //  1,024,000
    float* entL  = (float*)(ws + 105275392);   //    245,760 (120*512*4)
    u16*   entO  = (u16*)(ws + 105521152);     // 31,457,280 (120*512*256*2)
    float* relLL = (float*)(ws + 136978432);   //      8,192
    float* relLR = (float*)(ws + 136986624);   //      8,192
    u16*   relOL = (u16*)(ws + 136994816);     //  1,048,576
    u16*   relOR = (u16*)(ws + 138043392);     //  1,048,576
    const size_t WS_FULL = 139091968;          // <= 145,655,808 (established)
    const size_t WS_FALLBACK = 786432;

    prep_copy<<<dim3(384), dim3(256), 0, stream>>>(
        query, W_left, b_left, W_right, b_right, W_ent, b_ent,
        left_child, right_child, qe_bf, ql_bf, qr_bf, out);

    if (ws_size >= WS_FULL) {
        conv_fused<<<dim3(1595, 4), dim3(256), 0, stream>>>(
            ent_emb, rel_emb, entT, entB, relT, relB);
        flash8<<<dim3(512), dim3(256), 0, stream>>>(
            qe_bf, ql_bf, qr_bf, entB, relB, entT, relT,
            entL, relLL, relLR, entO, relOL, relOR);
        combine_all<<<dim3(64, 3), dim3(256), 0, stream>>>(
            entO, entL, relOL, relLL, relOR, relLR, out);
    } else if (ws_size >= WS_FALLBACK) {
        attend_simple<<<dim3(512), dim3(256), 0, stream>>>(qe_bf, ent_emb, ENT_N, out, 512, 393216);
        attend_simple<<<dim3(512), dim3(256), 0, stream>>>(ql_bf, rel_emb, REL_N, out, 256, -1);
        attend_simple<<<dim3(512), dim3(256), 0, stream>>>(qr_bf, rel_emb, REL_N, out, 393472, -1);
    }
    (void)in_sizes; (void)n_in; (void)out_size;
}

// Round 10
// 306.095 us; speedup vs baseline: 1.1307x; 1.0606x over previous
//
#include <hip/hip_runtime.h>
#include <hip/hip_bf16.h>
#include <math.h>

typedef __bf16 bf16;
typedef unsigned short u16;
typedef unsigned int u32;
typedef unsigned long long u64;
typedef long long i64;
typedef unsigned char u8;
typedef __attribute__((ext_vector_type(8))) __bf16 bf16x8;
typedef __attribute__((ext_vector_type(16))) float f32x16;
typedef __attribute__((address_space(1))) void gvoid;
typedef __attribute__((address_space(3))) void svoid;

#define ENT_N 100000
#define REL_N 2000
#define ENT_CH 120        // partial chunks per qt (ent)
#define REL_CH 4          // partial chunks per (side,qt) (rel)

// ---------------------------------------------------------------------------
// prep_copy: blocks 0..127 linear projections -> fp8 q (flash) + bf16 q
// (fallback); blocks 128..383 passthrough copies.
// ---------------------------------------------------------------------------
__global__ __launch_bounds__(256) void prep_copy(
    const float* __restrict__ query,
    const float* __restrict__ W_left, const float* __restrict__ b_left,
    const float* __restrict__ W_right, const float* __restrict__ b_right,
    const float* __restrict__ W_ent, const float* __restrict__ b_ent,
    const float* __restrict__ lc, const float* __restrict__ rc,
    bf16* __restrict__ qe, bf16* __restrict__ ql, bf16* __restrict__ qr,
    u8* __restrict__ qe8, u8* __restrict__ ql8, u8* __restrict__ qr8,
    float* __restrict__ out)
{
    __shared__ float qs[4 * 768];
    const int t = threadIdx.x;
    if (blockIdx.x >= 128) {
        const int idx = (blockIdx.x - 128) * 256 + t;
        if (idx < 32768) {
            const int q = idx >> 6, e4 = idx & 63;
            float4 v = *(const float4*)(lc + (size_t)q * 768 + e4 * 4);
            *(float4*)(out + (size_t)q * 768 + e4 * 4) = v;
        } else {
            const int j = idx - 32768;
            const int q = j >> 6, e4 = j & 63;
            float4 v = *(const float4*)(rc + (size_t)q * 768 + 512 + e4 * 4);
            *(float4*)(out + (size_t)393216 + q * 768 + 512 + e4 * 4) = v;
        }
        return;
    }
    const int b0 = blockIdx.x * 4;
#pragma unroll
    for (int i = 0; i < 12; ++i)
        qs[t + 256 * i] = query[(size_t)b0 * 768 + t + 256 * i];
    __syncthreads();

    const int j = t;
    float ae[4], al[4], ar[4];
    const float be = b_ent[j], bl = b_left[j], br = b_right[j];
#pragma unroll
    for (int r = 0; r < 4; ++r) { ae[r] = be; al[r] = bl; ar[r] = br; }

    const float* we = W_ent + (size_t)j * 768;
    for (int k = 0; k < 768; k += 4) {
        const float4 wv = *(const float4*)(we + k);
#pragma unroll
        for (int r = 0; r < 4; ++r) {
            const float* qq = qs + r * 768 + k;
            ae[r] += wv.x * qq[0] + wv.y * qq[1] + wv.z * qq[2] + wv.w * qq[3];
        }
    }
    const float* wl = W_left + (size_t)j * 256;
    const float* wr = W_right + (size_t)j * 256;
    for (int k = 0; k < 256; k += 4) {
        const float4 w1 = *(const float4*)(wl + k);
        const float4 w2 = *(const float4*)(wr + k);
#pragma unroll
        for (int r = 0; r < 4; ++r) {
            const float* qq = qs + r * 768 + 256 + k;
            al[r] += w1.x * qq[0] + w1.y * qq[1] + w1.z * qq[2] + w1.w * qq[3];
            ar[r] += w2.x * qq[0] + w2.y * qq[1] + w2.z * qq[2] + w2.w * qq[3];
        }
    }
#pragma unroll
    for (int r = 0; r < 4; ++r) {
        qe[(size_t)(b0 + r) * 256 + j] = (bf16)ae[r];
        ql[(size_t)(b0 + r) * 256 + j] = (bf16)al[r];
        qr[(size_t)(b0 + r) * 256 + j] = (bf16)ar[r];
        qe8[(size_t)(b0 + r) * 256 + j] =
            (u8)__builtin_amdgcn_cvt_pk_fp8_f32(ae[r], ae[r], 0, false);
        ql8[(size_t)(b0 + r) * 256 + j] =
            (u8)__builtin_amdgcn_cvt_pk_fp8_f32(al[r], al[r], 0, false);
        qr8[(size_t)(b0 + r) * 256 + j] =
            (u8)__builtin_amdgcn_cvt_pk_fp8_f32(ar[r], ar[r], 0, false);
    }
}

// ---------------------------------------------------------------------------
// conv_fused v4 (fp8): fp32 tables -> (a) row-major fp8 [R][256] (K operand,
// direct from staging regs) and (b) 32-row block-major fp8 V^T with rows
// permuted inside each block to the MFMA C-layout (same permutation as r9:
// table row (j&3)+8*(j>>2)+4*kb+16*ks2 at slot ks2*16+kb*8+j), so the P
// repack in flash is shuffle-free. Write traffic halves vs bf16.
// ---------------------------------------------------------------------------
__global__ __launch_bounds__(256) void conv_fused(
    const float* __restrict__ entF, const float* __restrict__ relF,
    u8* __restrict__ entT, u8* __restrict__ entB,
    u8* __restrict__ relT, u8* __restrict__ relB)
{
    const float* in; u8* outT; u8* outB; int R; int r0;
    if (blockIdx.x < 1563) {
        in = entF; outT = entT; outB = entB; R = ENT_N; r0 = blockIdx.x * 64;
    } else {
        in = relF; outT = relT; outB = relB; R = REL_N;
        r0 = (blockIdx.x - 1563) * 64;
    }
    __shared__ float tile[64 * 65];
    const int t = threadIdx.x;
    const int e0 = blockIdx.y * 64;

    const int eg = t & 7, rowb = t >> 3;
#pragma unroll
    for (int item = 0; item < 2; ++item) {
        const int r = rowb + item * 32;
        const bool valid = (r0 + r) < R;
        float4 a, b;
        if (valid) {
            const float* src = in + (size_t)(r0 + r) * 256 + e0 + eg * 8;
            a = *(const float4*)src;
            b = *(const float4*)(src + 4);
        } else { a = make_float4(0.f, 0.f, 0.f, 0.f); b = a; }
        float* dst = tile + r * 65 + eg * 8;
        dst[0] = a.x; dst[1] = a.y; dst[2] = a.z; dst[3] = a.w;
        dst[4] = b.x; dst[5] = b.y; dst[6] = b.z; dst[7] = b.w;
        if (valid) {
            u32 k0 = __builtin_amdgcn_cvt_pk_fp8_f32(a.x, a.y, 0, false);
            k0 = __builtin_amdgcn_cvt_pk_fp8_f32(a.z, a.w, k0, true);
            u32 k1 = __builtin_amdgcn_cvt_pk_fp8_f32(b.x, b.y, 0, false);
            k1 = __builtin_amdgcn_cvt_pk_fp8_f32(b.z, b.w, k1, true);
            uint2 kk; kk.x = k0; kk.y = k1;
            *(uint2*)(outB + (size_t)(r0 + r) * 256 + e0 + eg * 8) = kk;
        }
    }
    __syncthreads();

    // V emit with per-4-row-group permutation, 4 fp8 = one u32 per group
    const int el = t >> 2, rg = t & 3;
#pragma unroll
    for (int item = 0; item < 2; ++item) {
        const int rp = rg * 8 + item * 32;
        const int blk32 = (r0 + rp) >> 5;
#pragma unroll
        for (int h = 0; h < 2; ++h) {
            const int b = rg * 2 + h;
            const int rb = rp + 4 * h;
            u32 v = __builtin_amdgcn_cvt_pk_fp8_f32(
                tile[(rb + 0) * 65 + el], tile[(rb + 1) * 65 + el], 0, false);
            v = __builtin_amdgcn_cvt_pk_fp8_f32(
                tile[(rb + 2) * 65 + el], tile[(rb + 3) * 65 + el], v, true);
            const int rc = (b >> 2) * 2 + (b & 1);
            *(u32*)(outT + (size_t)blk32 * 8192 +
                    ((size_t)rc * 256 + e0 + el) * 8 + (b & 2) * 2) = v;
        }
    }
}

// ---------------------------------------------------------------------------
// flash9: fp8 end-to-end. flash8 structure (512-block balanced persistent
// grid, 32-row tiles, dbuf async staging, 2 blocks/CU) with fp8 operands:
// LDS reads/tile halve (A-frags 8 B/lane), staging halves (16 KB/tile),
// LDS 32 KB. Permuted-V layout keeps P repack shuffle-free (cvt_pk only).
// ---------------------------------------------------------------------------
__global__ __launch_bounds__(256, 2) void flash9(
    const u8* __restrict__ qeP, const u8* __restrict__ qlP,
    const u8* __restrict__ qrP,
    const u8* __restrict__ entB, const u8* __restrict__ relB,
    const u8* __restrict__ entT, const u8* __restrict__ relT,
    float* __restrict__ entL, float* __restrict__ relLL,
    float* __restrict__ relLR,
    u16* __restrict__ entO, u16* __restrict__ relOL, u16* __restrict__ relOR)
{
    const int tid = threadIdx.x;
    const int w = tid >> 6;
    const int lane = tid & 63;
    const int n = lane & 31;
    const int kb = lane >> 5;

    int qt, c, stride, nt, Nrows;
    const u8* qbf; const u8* tabB; const u8* tabT;
    float* pL; u16* pO;
    {
        const int id = blockIdx.x;
        if (id < 480) {
            qt = id / 120; c = id % 120;
            stride = 120; nt = (c < 5) ? 27 : 26;
            Nrows = ENT_N;
            qbf = qeP; tabB = entB; tabT = entT; pL = entL; pO = entO;
        } else {
            const int r = id - 480;
            qt = (r >> 2) & 3; c = r & 3;
            stride = 4; nt = (c < 3) ? 16 : 15;
            Nrows = REL_N;
            tabB = relB; tabT = relT;
            if (r < 16) { qbf = qlP; pL = relLL; pO = relOL; }
            else        { qbf = qrP; pL = relLR; pO = relOR; }
        }
    }
    const int q0 = qt * 128;
    const int qw = q0 + w * 32;

    // 32 KB LDS: buf{0,1} x (sK 8 KB [k16c 16][row 32]x16B + sV 8 KB
    // [rc 4][e 256]x8B). All accesses bank-balanced (b64 min-phase).
    __shared__ __align__(16) u8 lds[32768];
    u16* lds16 = (u16*)lds;

    const u8* qrow = qbf + (size_t)(qw + n) * 256;
    i64 qf[16];
#pragma unroll
    for (int ks = 0; ks < 16; ++ks)
        qf[ks] = *(const i64*)(qrow + ks * 16 + kb * 8);

    f32x16 acc[8];
#pragma unroll
    for (int et = 0; et < 8; ++et)
#pragma unroll
        for (int i = 0; i < 16; ++i) acc[et][i] = 0.f;
    float l_run = 0.f;

    auto stage = [&](int buf, int rt) {
        u8* sK = lds + buf * 16384;
        u8* sV = sK + 8192;
        // K: row-major fp8; lane covers (row = n, k16c = w*2 + kb [+8])
        const int rowc = min(rt * 32 + n, Nrows - 1);
        const u8* kbase = tabB + (size_t)rowc * 256 + (w * 2 + kb) * 16;
        __builtin_amdgcn_global_load_lds((gvoid*)kbase,
                                         (svoid*)(sK + w * 1024), 16, 0, 0);
        __builtin_amdgcn_global_load_lds((gvoid*)(kbase + 128),
                                         (svoid*)(sK + w * 1024 + 4096), 16, 0, 0);
        // V: contiguous 1 KB per wave from permuted block-major fp8
        const u8* vsrc = tabT + (size_t)rt * 8192 + w * 2048 + (size_t)lane * 16;
        __builtin_amdgcn_global_load_lds((gvoid*)vsrc,
                                         (svoid*)(sV + w * 2048), 16, 0, 0);
        __builtin_amdgcn_global_load_lds((gvoid*)(vsrc + 1024),
                                         (svoid*)(sV + w * 2048 + 1024), 16, 0, 0);
    };

    int rt = c;
    stage(0, rt);
    __syncthreads();

    for (int k = 0; k < nt; ++k) {
        if (k + 1 < nt) stage((k + 1) & 1, rt + stride);

        const u8* sK = lds + (k & 1) * 16384;
        const u8* sV = sK + 8192;
        const int gr = rt * 32;

        // ---- logits^T: D[row=m(table), col=n(q)] ----
        f32x16 L;
#pragma unroll
        for (int i = 0; i < 16; ++i) L[i] = 0.f;
#pragma unroll
        for (int ks = 0; ks < 16; ++ks) {
            i64 a = *(const i64*)(sK + ks * 512 + n * 16 + kb * 8);
            L = __builtin_amdgcn_mfma_f32_32x32x16_fp8_fp8(a, qf[ks], L, 0, 0, 0);
        }
        if (gr + 32 > Nrows) {
#pragma unroll
            for (int r = 0; r < 16; ++r) {
                const int row = (r & 3) + 8 * (r >> 2) + 4 * kb;
                if (gr + row >= Nrows) L[r] = -1e30f;
            }
        }
        // ---- P = exp(L) ----
        float rs = 0.f;
#pragma unroll
        for (int r = 0; r < 16; ++r) {
            const float p = __expf(L[r]);
            L[r] = p; rs += p;
        }
        rs += __shfl_xor(rs, 32);
        l_run += rs;
        // ---- P -> fp8 B-fragments (register order, no shuffles) ----
        u32 p0 = __builtin_amdgcn_cvt_pk_fp8_f32(L[0], L[1], 0, false);
        p0 = __builtin_amdgcn_cvt_pk_fp8_f32(L[2], L[3], p0, true);
        u32 p1 = __builtin_amdgcn_cvt_pk_fp8_f32(L[4], L[5], 0, false);
        p1 = __builtin_amdgcn_cvt_pk_fp8_f32(L[6], L[7], p1, true);
        u32 p2 = __builtin_amdgcn_cvt_pk_fp8_f32(L[8], L[9], 0, false);
        p2 = __builtin_amdgcn_cvt_pk_fp8_f32(L[10], L[11], p2, true);
        u32 p3 = __builtin_amdgcn_cvt_pk_fp8_f32(L[12], L[13], 0, false);
        p3 = __builtin_amdgcn_cvt_pk_fp8_f32(L[14], L[15], p3, true);
        const i64 bp0 = (i64)(((u64)p1 << 32) | (u64)p0);
        const i64 bp1 = (i64)(((u64)p3 << 32) | (u64)p2);
        // ---- PV: O^T += V^T x P ----
#pragma unroll
        for (int ks2 = 0; ks2 < 2; ++ks2) {
            const i64 bp = ks2 ? bp1 : bp0;
            const int rc = ks2 * 2 + kb;
#pragma unroll
            for (int et = 0; et < 8; ++et) {
                i64 av = *(const i64*)(sV + rc * 2048 + (et * 32 + n) * 8);
                acc[et] = __builtin_amdgcn_mfma_f32_32x32x16_fp8_fp8(av, bp, acc[et], 0, 0, 0);
            }
        }
        rt += stride;
        __syncthreads();
    }

    if (lane < 32) pL[(size_t)c * 512 + qw + n] = l_run;

    // ---- write partial O via LDS transpose (stride 264, two wave-pairs) ----
    for (int half = 0; half < 2; ++half) {
        __syncthreads();
        if ((w >> 1) == half) {
            u16* rgn = lds16 + (w & 1) * 8448;   // [32 q][264]
#pragma unroll
            for (int et = 0; et < 8; ++et)
#pragma unroll
                for (int a2 = 0; a2 < 4; ++a2) {
                    bf16 h0 = (bf16)acc[et][a2 * 4 + 0];
                    bf16 h1 = (bf16)acc[et][a2 * 4 + 1];
                    bf16 h2 = (bf16)acc[et][a2 * 4 + 2];
                    bf16 h3 = (bf16)acc[et][a2 * 4 + 3];
                    uint2 pk;
                    pk.x = ((u32)(*(u16*)&h1) << 16) | (u32)(*(u16*)&h0);
                    pk.y = ((u32)(*(u16*)&h3) << 16) | (u32)(*(u16*)&h2);
                    *(uint2*)(rgn + n * 264 + et * 32 + 8 * a2 + 4 * kb) = pk;
                }
        }
        __syncthreads();
#pragma unroll
        for (int rg = 0; rg < 2; ++rg) {
            const int qt2 = q0 + (half * 2 + rg) * 32;
            const u16* src = lds16 + rg * 8448;
            const int qq = tid >> 3, e0 = (tid & 7) * 32;
#pragma unroll
            for (int i = 0; i < 4; ++i) {
                const u16* sp = src + qq * 264 + e0 + i * 8;
                uint2 a = *(const uint2*)(sp);
                uint2 b = *(const uint2*)(sp + 4);
                uint4 wv; wv.x = a.x; wv.y = a.y; wv.z = b.x; wv.w = b.y;
                *(uint4*)(pO + ((size_t)c * 512 + qt2 + qq) * 256 + e0 + i * 8) = wv;
            }
        }
    }
}

// ---------------------------------------------------------------------------
// combine_all: grid (64, 3): y=0 ent (CH=120), y=1 relL, y=2 relR (CH=4).
// ---------------------------------------------------------------------------
__global__ __launch_bounds__(256) void combine_all(
    const u16* __restrict__ entO, const float* __restrict__ entL,
    const u16* __restrict__ relOL, const float* __restrict__ relLL,
    const u16* __restrict__ relOR, const float* __restrict__ relLR,
    float* __restrict__ out)
{
    const u16* pO; const float* pl; int CH, baseA, baseB;
    if (blockIdx.y == 0) { pO = entO; pl = entL; CH = ENT_CH; baseA = 512; baseB = 393216; }
    else if (blockIdx.y == 1) { pO = relOL; pl = relLL; CH = REL_CH; baseA = 256; baseB = -1; }
    else { pO = relOR; pl = relLR; CH = REL_CH; baseA = 393472; baseB = -1; }

    const int idx = blockIdx.x * 256 + threadIdx.x;
    const int q = idx >> 5;
    const int e0 = (idx & 31) * 8;
    float s = 0.f;
#pragma unroll 4
    for (int c = 0; c < CH; ++c) s += pl[(size_t)c * 512 + q];
    const float inv = 1.f / s;
    float a[8];
#pragma unroll
    for (int k = 0; k < 8; ++k) a[k] = 0.f;
#pragma unroll 4
    for (int c = 0; c < CH; ++c) {
        const uint4 wv = *(const uint4*)(pO + ((size_t)c * 512 + q) * 256 + e0);
        const u32 ww[4] = {wv.x, wv.y, wv.z, wv.w};
#pragma unroll
        for (int p = 0; p < 4; ++p) {
            a[p * 2]     += __uint_as_float((ww[p] & 0xffffu) << 16);
            a[p * 2 + 1] += __uint_as_float(ww[p] & 0xffff0000u);
        }
    }
#pragma unroll
    for (int k = 0; k < 8; ++k) a[k] *= inv;
    float4 o1 = {a[0], a[1], a[2], a[3]};
    float4 o2 = {a[4], a[5], a[6], a[7]};
    *(float4*)(out + (size_t)baseA + (size_t)q * 768 + e0) = o1;
    *(float4*)(out + (size_t)baseA + (size_t)q * 768 + e0 + 4) = o2;
    if (baseB >= 0) {
        *(float4*)(out + (size_t)baseB + (size_t)q * 768 + e0) = o1;
        *(float4*)(out + (size_t)baseB + (size_t)q * 768 + e0 + 4) = o2;
    }
}

// ---------------------------------------------------------------------------
// Fallback (small ws): fp32 online-softmax attend, bf16 q input.
// ---------------------------------------------------------------------------
__global__ __launch_bounds__(256) void attend_simple(
    const bf16* __restrict__ qbf, const float* __restrict__ tab, int Nrows,
    float* __restrict__ out, int baseA, int baseB)
{
    const int q = blockIdx.x;
    const int t = threadIdx.x, wave = t >> 6, lane = t & 63;
    float qv[4];
#pragma unroll
    for (int i = 0; i < 4; ++i) qv[i] = (float)qbf[(size_t)q * 256 + lane + 64 * i];
    float m = -INFINITY, l = 0.f, o[4] = {0.f, 0.f, 0.f, 0.f};
    for (int r = wave; r < Nrows; r += 4) {
        const float* row = tab + (size_t)r * 256;
        float d = 0.f;
#pragma unroll
        for (int i = 0; i < 4; ++i) d += qv[i] * row[lane + 64 * i];
#pragma unroll
        for (int s = 32; s; s >>= 1) d += __shfl_xor(d, s);
        const float mn = fmaxf(m, d);
        const float al = __expf(m - mn);
        const float p = __expf(d - mn);
#pragma unroll
        for (int i = 0; i < 4; ++i) o[i] = o[i] * al + p * row[lane + 64 * i];
        l = l * al + p; m = mn;
    }
    __shared__ float sm[4], sl[4], so[4][256];
    if (lane == 0) { sm[wave] = m; sl[wave] = l; }
#pragma unroll
    for (int i = 0; i < 4; ++i) so[wave][lane + 64 * i] = o[i];
    __syncthreads();
    const float M = fmaxf(fmaxf(sm[0], sm[1]), fmaxf(sm[2], sm[3]));
    const float w0 = __expf(sm[0] - M), w1 = __expf(sm[1] - M);
    const float w2 = __expf(sm[2] - M), w3 = __expf(sm[3] - M);
    const float L = w0 * sl[0] + w1 * sl[1] + w2 * sl[2] + w3 * sl[3];
    const float a = (w0 * so[0][t] + w1 * so[1][t] + w2 * so[2][t] + w3 * so[3][t]) / L;
    out[(size_t)baseA + (size_t)q * 768 + t] = a;
    if (baseB >= 0) out[(size_t)baseB + (size_t)q * 768 + t] = a;
}

// ---------------------------------------------------------------------------
extern "C" void kernel_launch(void* const* d_in, const int* in_sizes, int n_in,
                              void* d_out, int out_size, void* d_ws, size_t ws_size,
                              hipStream_t stream)
{
    const float* left_child  = (const float*)d_in[0];
    const float* right_child = (const float*)d_in[1];
    const float* query       = (const float*)d_in[2];
    const float* ent_emb     = (const float*)d_in[3];
    const float* rel_emb     = (const float*)d_in[4];
    const float* W_left      = (const float*)d_in[5];
    const float* b_left      = (const float*)d_in[6];
    const float* W_right     = (const float*)d_in[7];
    const float* b_right     = (const float*)d_in[8];
    const float* W_ent       = (const float*)d_in[9];
    const float* b_ent       = (const float*)d_in[10];
    float* out = (float*)d_out;
    char* ws = (char*)d_ws;

    // ws layout (bytes)
    bf16* qe_bf = (bf16*)(ws + 0);           //    262,144 (fallback)
    bf16* ql_bf = (bf16*)(ws + 262144);      //    262,144
    bf16* qr_bf = (bf16*)(ws + 524288);      //    262,144
    u8*   qe8   = (u8*)(ws + 786432);        //    131,072
    u8*   ql8   = (u8*)(ws + 917504);        //    131,072
    u8*   qr8   = (u8*)(ws + 1048576);       //    131,072
    u8*   entT8 = (u8*)(ws + 1179648);       // 25,608,192 (3126 blk32 x 8 KB)
    u8*   relT8 = (u8*)(ws + 26787840);      //    524,288 (64 blk32 x 8 KB)
    u8*   entB8 = (u8*)(ws + 27312128);      // 25,600,000
    u8*   relB8 = (u8*)(ws + 52912128);      //    512,000
    float* entL = (float*)(ws + 53424128);   //    245,760 (120*512*4)
    u16*  entO  = (u16*)(ws + 53669888);     // 31,457,280 (120*512*256*2)
    float* relLL = (float*)(ws + 85127168);  //      8,192
    float* relLR = (float*)(ws + 85135360);  //      8,192
    u16*  relOL = (u16*)(ws + 85143552);     //  1,048,576
    u16*  relOR = (u16*)(ws + 86192128);     //  1,048,576
    const size_t WS_FULL = 87240704;         // < previously-working 139 MB
    const size_t WS_FALLBACK = 786432;

    prep_copy<<<dim3(384), dim3(256), 0, stream>>>(
        query, W_left, b_left, W_right, b_right, W_ent, b_ent,
        left_child, right_child, qe_bf, ql_bf, qr_bf, qe8, ql8, qr8, out);

    if (ws_size >= WS_FULL) {
        conv_fused<<<dim3(1595, 4), dim3(256), 0, stream>>>(
            ent_emb, rel_emb, entT8, entB8, relT8, relB8);
        flash9<<<dim3(512), dim3(256), 0, stream>>>(
            qe8, ql8, qr8, entB8, relB8, entT8, relT8,
            entL, relLL, relLR, entO, relOL, relOR);
        combine_all<<<dim3(64, 3), dim3(256), 0, stream>>>(
            entO, entL, relOL, relLL, relOR, relLR, out);
    } else if (ws_size >= WS_FALLBACK) {
        attend_simple<<<dim3(512), dim3(256), 0, stream>>>(qe_bf, ent_emb, ENT_N, out, 512, 393216);
        attend_simple<<<dim3(512), dim3(256), 0, stream>>>(ql_bf, rel_emb, REL_N, out, 256, -1);
        attend_simple<<<dim3(512), dim3(256), 0, stream>>>(qr_bf, rel_emb, REL_N, out, 393472, -1);
    }
    (void)in_sizes; (void)n_in; (void)out_size;
}